// Round 5
// baseline (691.520 us; speedup 1.0000x reference)
//
#include <hip/hip_runtime.h>
#include <hip/hip_bf16.h>

#define D 256
#define K 8192
#define NTOT 32768
#define BM 128
#define BN2 128
#define CSPLIT 4
#define CT_PER (K / CSPLIT / BN2)  // 16 code-tiles per block

typedef __bf16 bf16x8 __attribute__((ext_vector_type(8)));
typedef float f32x4 __attribute__((ext_vector_type(4)));

__device__ __forceinline__ void gl_lds16(const void* g, void* l) {
    __builtin_amdgcn_global_load_lds(
        (__attribute__((address_space(1))) void*)(g),
        (__attribute__((address_space(3))) void*)(l), 16, 0, 0);
}

__device__ __forceinline__ unsigned int enc_f32(float f) {
    unsigned int u = __float_as_uint(f);
    return (u & 0x80000000u) ? ~u : (u | 0x80000000u);
}

__device__ __forceinline__ unsigned short f2bfu(float x) {
    __hip_bfloat16 h = __float2bfloat16(x);
    return __builtin_bit_cast(unsigned short, h);
}
__device__ __forceinline__ float bfu2f(unsigned short u) {
    return __bfloat162float(__builtin_bit_cast(__hip_bfloat16, u));
}

// ---------- z -> Fhi/Flo bf16 [NTOT, D] ----------
__global__ __launch_bounds__(256)
void conv_F(const float* __restrict__ z, unsigned short* __restrict__ Fhi,
            unsigned short* __restrict__ Flo) {
    int i4 = blockIdx.x * 256 + threadIdx.x;
    float4 v = ((const float4*)z)[i4];
    ushort4 h, l;
    h.x = f2bfu(v.x); l.x = f2bfu(v.x - bfu2f(h.x));
    h.y = f2bfu(v.y); l.y = f2bfu(v.y - bfu2f(h.y));
    h.z = f2bfu(v.z); l.z = f2bfu(v.z - bfu2f(h.z));
    h.w = f2bfu(v.w); l.w = f2bfu(v.w - bfu2f(h.w));
    ((ushort4*)Fhi)[i4] = h;
    ((ushort4*)Flo)[i4] = l;
}

// ---------- embed [D,K] -> EhiT/EloT bf16 [K,D] + ET fp32 [K,D] ----------
__global__ __launch_bounds__(256)
void conv_E(const float* __restrict__ E, unsigned short* __restrict__ EhiT,
            unsigned short* __restrict__ EloT, float* __restrict__ ET) {
    __shared__ float tile[64][65];
    int tid = threadIdx.x;
    int k0 = blockIdx.x * 64, d0 = blockIdx.y * 64;
#pragma unroll
    for (int it = 0; it < 16; ++it) {
        int idx = it * 256 + tid;
        int dr = idx >> 6, kc = idx & 63;
        tile[kc][dr] = E[(d0 + dr) * K + k0 + kc];
    }
    __syncthreads();
#pragma unroll
    for (int it = 0; it < 16; ++it) {
        int idx = it * 256 + tid;
        int kr = idx >> 6, dc = idx & 63;
        float v = tile[kr][dc];
        unsigned short h = f2bfu(v);
        int o = (k0 + kr) * D + d0 + dc;
        EhiT[o] = h;
        EloT[o] = f2bfu(v - bfu2f(h));
        ET[o] = v;
    }
}

// ---------- enorm[k] = sum_d E[d,k]^2 ----------
__global__ __launch_bounds__(256)
void enorm_kernel(const float* __restrict__ E, float* __restrict__ enorm) {
    int k = blockIdx.x * 256 + threadIdx.x;
    float s = 0.f;
    for (int d = 0; d < D; ++d) {
        float v = E[d * K + k];
        s += v * v;
    }
    enorm[k] = s;
}

// ---------- MFMA dist + fused argmin ----------
// 32 KB LDS: two 16 KB half-stage buffers (hi: Ah,Bh / lo: Al,Bl), swizzled,
// one barrier per half-stage, prefetch issued one half-stage ahead.
__global__ __launch_bounds__(256)
void mfma_dist_argmin(const unsigned short* __restrict__ Fhi,
                      const unsigned short* __restrict__ Flo,
                      const unsigned short* __restrict__ EhiT,
                      const unsigned short* __restrict__ EloT,
                      const float* __restrict__ enorm,
                      unsigned long long* __restrict__ bestpack) {
    // [buf: 0=hi,1=lo][array: A,B][128 rows x 32 d-elements]
    __shared__ unsigned short lds[2][2][BM * 32];

    const int tid = threadIdx.x;
    const int wave = tid >> 6;
    const int lane = tid & 63;
    const int qd = lane >> 4;   // 0..3
    const int ln = lane & 15;   // 0..15
    const int wm = (wave >> 1) * 64;
    const int wn = (wave & 1) * 64;
    const int n0 = blockIdx.x * BM;
    const int c0 = blockIdx.y * (K / CSPLIT);

    // staging: lane tid -> physical slot (row tid>>2, chunk tid&3) per 64-row half;
    // swizzle: physical chunk c holds logical chunk c ^ ((row>>1)&3)
    const int r_ = tid >> 2;
    const int s_sw = (tid & 3) ^ ((tid >> 3) & 3);

    // fragment read offsets; logical chunk qd -> physical qd^((row>>1)&3)
    const int csw = (qd ^ ((ln >> 1) & 3)) * 8;
    int aro[4], bro[4];
#pragma unroll
    for (int mi = 0; mi < 4; ++mi) aro[mi] = (wm + mi * 16 + ln) * 32 + csw;
#pragma unroll
    for (int ni = 0; ni < 4; ++ni) bro[ni] = (wn + ni * 16 + ln) * 32 + csw;

    float bestv[16];
    int besti[16];
#pragma unroll
    for (int i = 0; i < 16; ++i) { bestv[i] = 3.402823466e38f; besti[i] = 0; }

    auto load_half = [&](int buf, int ct, int d0, int lo) {
        const int cb0 = c0 + ct * BN2;
        const unsigned short* SA = lo ? Flo : Fhi;
        const unsigned short* SB = lo ? EloT : EhiT;
#pragma unroll
        for (int it = 0; it < 2; ++it) {
            const int ga = (n0 + it * 64 + r_) * D + d0 + s_sw * 8;
            const int gb = (cb0 + it * 64 + r_) * D + d0 + s_sw * 8;
            const int lo_off = it * 2048 + wave * 512;
            gl_lds16(SA + ga, &lds[buf][0][lo_off]);
            gl_lds16(SB + gb, &lds[buf][1][lo_off]);
        }
    };

    load_half(0, 0, 0, 0);  // prologue: hi of (ct=0, d0=0)

    for (int ct = 0; ct < CT_PER; ++ct) {
        const int cb = c0 + ct * BN2;
        float en[4];
#pragma unroll
        for (int ni = 0; ni < 4; ++ni) en[ni] = enorm[cb + wn + ni * 16 + ln];

        f32x4 acc[4][4];
#pragma unroll
        for (int mi = 0; mi < 4; ++mi)
#pragma unroll
            for (int ni = 0; ni < 4; ++ni) acc[mi][ni] = (f32x4){0.f, 0.f, 0.f, 0.f};

#pragma unroll
        for (int dd = 0; dd < 8; ++dd) {
            const int d0 = dd * 32;
            __syncthreads();  // hi buf ready; prior lo-buf reads done
            load_half(1, ct, d0, 1);  // prefetch lo half of this stage

            bf16x8 ah[4], bh[4];
#pragma unroll
            for (int mi = 0; mi < 4; ++mi) ah[mi] = *(const bf16x8*)&lds[0][0][aro[mi]];
#pragma unroll
            for (int ni = 0; ni < 4; ++ni) bh[ni] = *(const bf16x8*)&lds[0][1][bro[ni]];
#pragma unroll
            for (int mi = 0; mi < 4; ++mi)
#pragma unroll
                for (int ni = 0; ni < 4; ++ni)
                    acc[mi][ni] = __builtin_amdgcn_mfma_f32_16x16x32_bf16(
                        ah[mi], bh[ni], acc[mi][ni], 0, 0, 0);

            __syncthreads();  // lo buf ready; hi-buf reads done
            // prefetch hi half of the next stage
            int nct = ct, ndd = dd + 1;
            if (ndd == 8) { ndd = 0; nct = ct + 1; }
            if (nct < CT_PER) load_half(0, nct, ndd * 32, 0);

            bf16x8 al[4], bl[4];
#pragma unroll
            for (int mi = 0; mi < 4; ++mi) al[mi] = *(const bf16x8*)&lds[1][0][aro[mi]];
#pragma unroll
            for (int ni = 0; ni < 4; ++ni) bl[ni] = *(const bf16x8*)&lds[1][1][bro[ni]];
#pragma unroll
            for (int mi = 0; mi < 4; ++mi)
#pragma unroll
                for (int ni = 0; ni < 4; ++ni)
                    acc[mi][ni] = __builtin_amdgcn_mfma_f32_16x16x32_bf16(
                        ah[mi], bl[ni], acc[mi][ni], 0, 0, 0);
#pragma unroll
            for (int mi = 0; mi < 4; ++mi)
#pragma unroll
                for (int ni = 0; ni < 4; ++ni)
                    acc[mi][ni] = __builtin_amdgcn_mfma_f32_16x16x32_bf16(
                        al[mi], bh[ni], acc[mi][ni], 0, 0, 0);
        }

        // fold this code-tile into running per-row best
#pragma unroll
        for (int ni = 0; ni < 4; ++ni) {
            int k = cb + wn + ni * 16 + ln;
#pragma unroll
            for (int mi = 0; mi < 4; ++mi) {
                f32x4 a = acc[mi][ni];
#pragma unroll
                for (int r = 0; r < 4; ++r) {
                    float dist = en[ni] - 2.0f * a[r];
                    int bi = mi * 4 + r;
                    if (dist < bestv[bi]) { bestv[bi] = dist; besti[bi] = k; }
                }
            }
        }
    }

    // reduce across the 16 lanes sharing a row, then atomic merge
#pragma unroll
    for (int mi = 0; mi < 4; ++mi) {
#pragma unroll
        for (int r = 0; r < 4; ++r) {
            int bi = mi * 4 + r;
            float v = bestv[bi];
            int ix = besti[bi];
#pragma unroll
            for (int off = 1; off < 16; off <<= 1) {
                float v2 = __shfl_xor(v, off);
                int i2 = __shfl_xor(ix, off);
                if (v2 < v || (v2 == v && i2 < ix)) { v = v2; ix = i2; }
            }
            if (ln == 0) {
                int m = n0 + wm + mi * 16 + qd * 4 + r;
                unsigned long long pack =
                    ((unsigned long long)enc_f32(v) << 32) | (unsigned int)ix;
                atomicMin(&bestpack[m], pack);
            }
        }
    }
}

// ---------- gather quantize, diff partial, segment-sum scatter ----------
#define ROWS_PER_BLOCK 64
__global__ __launch_bounds__(256)
void assign_apply(const float* __restrict__ z,   // [NTOT, D]
                  const float* __restrict__ ET,  // [K, D]
                  const unsigned long long* __restrict__ bestpack,
                  float* __restrict__ out_q, float* __restrict__ out_ind,
                  float* __restrict__ out_diff,
                  float* __restrict__ counts, float* __restrict__ esumT) {
    const int tx = threadIdx.x;  // = d
    const int rbase = blockIdx.x * ROWS_PER_BLOCK;
    float part = 0.f;
    for (int r = 0; r < ROWS_PER_BLOCK; ++r) {
        int n = rbase + r;
        unsigned long long p = bestpack[n];
        int idx = (int)(p & 0xFFFFFFFFull);
        float f = z[n * D + tx];
        float q = ET[idx * D + tx];
        out_q[n * D + tx] = q;
        float dd = q - f;
        part += dd * dd;
        atomicAdd(&esumT[idx * D + tx], f);
        if (tx == 0) {
            atomicAdd(&counts[idx], 1.0f);
            out_ind[n] = (float)idx;
        }
    }
#pragma unroll
    for (int off = 32; off; off >>= 1) part += __shfl_down(part, off);
    __shared__ float wsum[4];
    if ((tx & 63) == 0) wsum[tx >> 6] = part;
    __syncthreads();
    if (tx == 0) {
        float t = wsum[0] + wsum[1] + wsum[2] + wsum[3];
        atomicAdd(out_diff, t * (0.25f / 8388608.0f));
    }
}

// ---------- cluster_size_new + total n ----------
__global__ __launch_bounds__(1024)
void csn_sum(const float* __restrict__ cs_in, const float* __restrict__ counts,
             float* __restrict__ csn, float* __restrict__ nsum) {
    const float decay = 0.99f;
    const float omd = 0.01f;
    int tx = threadIdx.x;
    float p = 0.f;
    for (int k = tx; k < K; k += 1024) {
        float v = decay * cs_in[k] + omd * counts[k];
        csn[k] = v;
        p += v;
    }
#pragma unroll
    for (int off = 32; off; off >>= 1) p += __shfl_down(p, off);
    __shared__ float red[16];
    if ((tx & 63) == 0) red[tx >> 6] = p;
    __syncthreads();
    if (tx == 0) {
        float t = 0.f;
        for (int i = 0; i < 16; ++i) t += red[i];
        nsum[0] = t;
    }
}

// ---------- embed_new = (decay*eavg + (1-decay)*esum) / cs ----------
__global__ __launch_bounds__(256)
void finalize(const float* __restrict__ eavg, const float* __restrict__ esumT,
              const float* __restrict__ csn, const float* __restrict__ nsum,
              float* __restrict__ out_enew) {
    const float decay = 0.99f;
    const float omd = 0.01f;
    const float keps = (float)(8192 * 1e-5);
    int idx = blockIdx.x * 256 + threadIdx.x;  // d*K + k
    float nv = nsum[0];
    int k = idx & (K - 1);
    int d = idx >> 13;
    float avg_new = decay * eavg[idx] + omd * esumT[k * D + d];
    float cs = (csn[k] + 1e-5f) / (nv + keps) * nv;
    out_enew[idx] = avg_new / cs;
}

extern "C" void kernel_launch(void* const* d_in, const int* in_sizes, int n_in,
                              void* d_out, int out_size, void* d_ws, size_t ws_size,
                              hipStream_t stream) {
    const float* z = (const float*)d_in[0];      // [32,32,32,256]
    const float* embed = (const float*)d_in[1];  // [256, 8192]
    const float* cs_in = (const float*)d_in[2];  // [8192]
    const float* eavg = (const float*)d_in[3];   // [256, 8192]

    float* out = (float*)d_out;
    float* out_q = out;                  // 8388608
    float* out_diff = out + 8388608;     // 1
    float* out_ind = out + 8388609;      // 32768
    float* out_enew = out + 8421377;     // 2097152

    char* ws = (char*)d_ws;
    unsigned long long* bestpack = (unsigned long long*)ws;      // 256 KB
    float* enorm = (float*)(ws + 262144);                        // 32 KB
    float* counts = (float*)(ws + 294912);                       // 32 KB
    float* csn = (float*)(ws + 327680);                          // 32 KB
    float* nsum = (float*)(ws + 360448);                         // pad
    float* esumT = (float*)(ws + 360704);                        // 8 MB [K,D]
    unsigned short* Fhi = (unsigned short*)(ws + 8749312);       // 16 MB
    unsigned short* Flo = (unsigned short*)(ws + 25526528);      // 16 MB
    unsigned short* EhiT = (unsigned short*)(ws + 42303744);     // 4 MB
    unsigned short* EloT = (unsigned short*)(ws + 46498048);     // 4 MB
    float* ET = (float*)(ws + 50692352);                         // 8 MB

    hipMemsetAsync(bestpack, 0xFF, NTOT * 8, stream);
    hipMemsetAsync(counts, 0, K * 4, stream);
    hipMemsetAsync(esumT, 0, K * D * 4, stream);
    hipMemsetAsync(out_diff, 0, 4, stream);

    conv_F<<<NTOT * D / 4 / 256, 256, 0, stream>>>(z, Fhi, Flo);
    conv_E<<<dim3(K / 64, D / 64), 256, 0, stream>>>(embed, EhiT, EloT, ET);
    enorm_kernel<<<K / 256, 256, 0, stream>>>(embed, enorm);
    mfma_dist_argmin<<<dim3(NTOT / BM, CSPLIT), 256, 0, stream>>>(Fhi, Flo, EhiT, EloT,
                                                                  enorm, bestpack);
    assign_apply<<<NTOT / ROWS_PER_BLOCK, 256, 0, stream>>>(z, ET, bestpack, out_q,
                                                            out_ind, out_diff, counts, esumT);
    csn_sum<<<1, 1024, 0, stream>>>(cs_in, counts, csn, nsum);
    finalize<<<(D * K) / 256, 256, 0, stream>>>(eavg, esumT, csn, nsum, out_enew);
}

// Round 6
// 598.100 us; speedup vs baseline: 1.1562x; 1.1562x over previous
//
#include <hip/hip_runtime.h>
#include <hip/hip_bf16.h>

#define D 256
#define K 8192
#define NTOT 32768
#define BM 128
#define BN2 128
#define BD 32
#define CSPLIT 4
#define CT_PER (K / CSPLIT / BN2)  // 16 code-tiles per block

typedef __bf16 bf16x8 __attribute__((ext_vector_type(8)));
typedef float f32x4 __attribute__((ext_vector_type(4)));

__device__ __forceinline__ void gl_lds16(const void* g, void* l) {
    __builtin_amdgcn_global_load_lds(
        (__attribute__((address_space(1))) void*)(g),
        (__attribute__((address_space(3))) void*)(l), 16, 0, 0);
}

__device__ __forceinline__ unsigned int enc_f32(float f) {
    unsigned int u = __float_as_uint(f);
    return (u & 0x80000000u) ? ~u : (u | 0x80000000u);
}

__device__ __forceinline__ unsigned short f2bfu(float x) {
    __hip_bfloat16 h = __float2bfloat16(x);
    return __builtin_bit_cast(unsigned short, h);
}
__device__ __forceinline__ float bfu2f(unsigned short u) {
    return __bfloat162float(__builtin_bit_cast(__hip_bfloat16, u));
}

// ---------- z -> Fhi/Flo bf16 [NTOT, D] ----------
__global__ __launch_bounds__(256)
void conv_F(const float* __restrict__ z, unsigned short* __restrict__ Fhi,
            unsigned short* __restrict__ Flo) {
    int i4 = blockIdx.x * 256 + threadIdx.x;
    float4 v = ((const float4*)z)[i4];
    ushort4 h, l;
    h.x = f2bfu(v.x); l.x = f2bfu(v.x - bfu2f(h.x));
    h.y = f2bfu(v.y); l.y = f2bfu(v.y - bfu2f(h.y));
    h.z = f2bfu(v.z); l.z = f2bfu(v.z - bfu2f(h.z));
    h.w = f2bfu(v.w); l.w = f2bfu(v.w - bfu2f(h.w));
    ((ushort4*)Fhi)[i4] = h;
    ((ushort4*)Flo)[i4] = l;
}

// ---------- embed [D,K] -> EhiT/EloT bf16 [K,D] + ET fp32 [K,D] + enorm ----------
__global__ __launch_bounds__(256)
void conv_E(const float* __restrict__ E, unsigned short* __restrict__ EhiT,
            unsigned short* __restrict__ EloT, float* __restrict__ ET,
            float* __restrict__ enorm) {
    __shared__ float tile[64][65];
    int tid = threadIdx.x;
    int k0 = blockIdx.x * 64, d0 = blockIdx.y * 64;
#pragma unroll
    for (int it = 0; it < 16; ++it) {
        int idx = it * 256 + tid;
        int dr = idx >> 6, kc = idx & 63;
        tile[kc][dr] = E[(d0 + dr) * K + k0 + kc];
    }
    __syncthreads();
    float psum[4];
#pragma unroll
    for (int it = 0; it < 16; ++it) {
        int idx = it * 256 + tid;
        int kr = idx >> 6, dc = idx & 63;
        float v = tile[kr][dc];
        unsigned short h = f2bfu(v);
        int o = (k0 + kr) * D + d0 + dc;
        EhiT[o] = h;
        EloT[o] = f2bfu(v - bfu2f(h));
        ET[o] = v;
        psum[it & 3] = (it < 4 ? 0.f : psum[it & 3]) + v * v;
    }
    // each thread handled 4 rows (kr = tid>>6 + it/4*... ) -- reduce per-k partial
    // lanes with same kr: tid>>6 fixed per it-group; sum across dc via shfl (64 lanes = one row)
#pragma unroll
    for (int g = 0; g < 4; ++g) {
        float p = psum[g];
#pragma unroll
        for (int off = 32; off; off >>= 1) p += __shfl_down(p, off);
        if ((tid & 63) == 0) {
            int kr = g * 4 + (tid >> 6);
            atomicAdd(&enorm[k0 + kr * 4 + 0], 0.f);  // placeholder avoid misuse
        }
    }
}

// NOTE: the fused enorm above is subtle; use a dedicated simple kernel instead.
__global__ __launch_bounds__(256)
void enorm_kernel(const float* __restrict__ ET, float* __restrict__ enorm) {
    // ET is [K, D] row-major: row-sum of squares, one wave per 16 rows? simple:
    // one thread per k, strided over D with float4 (coalesced within wave? no —
    // each thread reads a contiguous row; acceptable: 8 MB L2-resident)
    int k = blockIdx.x * 256 + threadIdx.x;
    const float4* row = (const float4*)(ET + k * D);
    float s = 0.f;
#pragma unroll
    for (int d = 0; d < D / 4; ++d) {
        float4 v = row[d];
        s += v.x * v.x + v.y * v.y + v.z * v.z + v.w * v.w;
    }
    enorm[k] = s;
}

// ---------- MFMA dist + fused argmin (R2 structure + XOR bank swizzle) ----------
__global__ __launch_bounds__(256)
void mfma_dist_argmin(const unsigned short* __restrict__ Fhi,
                      const unsigned short* __restrict__ Flo,
                      const unsigned short* __restrict__ EhiT,
                      const unsigned short* __restrict__ EloT,
                      const float* __restrict__ enorm,
                      unsigned long long* __restrict__ bestpack) {
    __shared__ unsigned short Ah[BM * BD], Al[BM * BD], Bh[BN2 * BD], Bl[BN2 * BD];

    const int tid = threadIdx.x;
    const int wave = tid >> 6;
    const int lane = tid & 63;
    const int qd = lane >> 4;
    const int ln = lane & 15;
    const int wm = (wave >> 1) * 64;
    const int wn = (wave & 1) * 64;
    const int n0 = blockIdx.x * BM;
    const int c0 = blockIdx.y * (K / CSPLIT);
    // staging: lane tid -> physical (row tid>>2, chunk tid&3); swizzled global chunk
    const int r_ = tid >> 2;
    const int s_sw = (tid & 3) ^ ((tid >> 3) & 3);
    // read swizzle: logical chunk qd of row ln lives at physical chunk qd^((ln>>1)&3)
    const int csw = (qd ^ ((ln >> 1) & 3)) * 8;

    float bestv[16];
    int besti[16];
#pragma unroll
    for (int i = 0; i < 16; ++i) { bestv[i] = 3.402823466e38f; besti[i] = 0; }

    for (int ct = 0; ct < CT_PER; ++ct) {
        const int cb = c0 + ct * BN2;
        f32x4 acc[4][4];
#pragma unroll
        for (int mi = 0; mi < 4; ++mi)
#pragma unroll
            for (int ni = 0; ni < 4; ++ni) acc[mi][ni] = (f32x4){0.f, 0.f, 0.f, 0.f};

        for (int d0 = 0; d0 < D; d0 += BD) {
            __syncthreads();
#pragma unroll
            for (int it = 0; it < 2; ++it) {
                const int ga = (n0 + it * 64 + r_) * D + d0 + s_sw * 8;
                const int gb = (cb + it * 64 + r_) * D + d0 + s_sw * 8;
                const int lo = it * 2048 + wave * 512;
                gl_lds16(Fhi + ga, &Ah[lo]);
                gl_lds16(Flo + ga, &Al[lo]);
                gl_lds16(EhiT + gb, &Bh[lo]);
                gl_lds16(EloT + gb, &Bl[lo]);
            }
            __syncthreads();

            bf16x8 ah[4], al[4], bh[4], bl[4];
#pragma unroll
            for (int mi = 0; mi < 4; ++mi) {
                int off = (wm + mi * 16 + ln) * BD + csw;
                ah[mi] = *(const bf16x8*)&Ah[off];
                al[mi] = *(const bf16x8*)&Al[off];
            }
#pragma unroll
            for (int ni = 0; ni < 4; ++ni) {
                int off = (wn + ni * 16 + ln) * BD + csw;
                bh[ni] = *(const bf16x8*)&Bh[off];
                bl[ni] = *(const bf16x8*)&Bl[off];
            }
#pragma unroll
            for (int mi = 0; mi < 4; ++mi)
#pragma unroll
                for (int ni = 0; ni < 4; ++ni)
                    acc[mi][ni] = __builtin_amdgcn_mfma_f32_16x16x32_bf16(
                        ah[mi], bh[ni], acc[mi][ni], 0, 0, 0);
#pragma unroll
            for (int mi = 0; mi < 4; ++mi)
#pragma unroll
                for (int ni = 0; ni < 4; ++ni)
                    acc[mi][ni] = __builtin_amdgcn_mfma_f32_16x16x32_bf16(
                        ah[mi], bl[ni], acc[mi][ni], 0, 0, 0);
#pragma unroll
            for (int mi = 0; mi < 4; ++mi)
#pragma unroll
                for (int ni = 0; ni < 4; ++ni)
                    acc[mi][ni] = __builtin_amdgcn_mfma_f32_16x16x32_bf16(
                        al[mi], bh[ni], acc[mi][ni], 0, 0, 0);
        }

        float en[4];
#pragma unroll
        for (int ni = 0; ni < 4; ++ni) en[ni] = enorm[cb + wn + ni * 16 + ln];
#pragma unroll
        for (int ni = 0; ni < 4; ++ni) {
            int k = cb + wn + ni * 16 + ln;
#pragma unroll
            for (int mi = 0; mi < 4; ++mi) {
                f32x4 a = acc[mi][ni];
#pragma unroll
                for (int r = 0; r < 4; ++r) {
                    float dist = en[ni] - 2.0f * a[r];
                    int bi = mi * 4 + r;
                    if (dist < bestv[bi]) { bestv[bi] = dist; besti[bi] = k; }
                }
            }
        }
    }

#pragma unroll
    for (int mi = 0; mi < 4; ++mi) {
#pragma unroll
        for (int r = 0; r < 4; ++r) {
            int bi = mi * 4 + r;
            float v = bestv[bi];
            int ix = besti[bi];
#pragma unroll
            for (int off = 1; off < 16; off <<= 1) {
                float v2 = __shfl_xor(v, off);
                int i2 = __shfl_xor(ix, off);
                if (v2 < v || (v2 == v && i2 < ix)) { v = v2; ix = i2; }
            }
            if (ln == 0) {
                int m = n0 + wm + mi * 16 + qd * 4 + r;
                unsigned long long pack =
                    ((unsigned long long)enc_f32(v) << 32) | (unsigned int)ix;
                atomicMin(&bestpack[m], pack);
            }
        }
    }
}

// ---------- gather quantize, diff partial, segment-sum scatter ----------
#define ROWS_PER_BLOCK 64
__global__ __launch_bounds__(256)
void assign_apply(const float* __restrict__ z,   // [NTOT, D]
                  const float* __restrict__ ET,  // [K, D]
                  const unsigned long long* __restrict__ bestpack,
                  float* __restrict__ out_q, float* __restrict__ out_ind,
                  float* __restrict__ out_diff,
                  float* __restrict__ counts, float* __restrict__ esumT) {
    const int tx = threadIdx.x;  // = d
    const int rbase = blockIdx.x * ROWS_PER_BLOCK;
    float part = 0.f;
    for (int r = 0; r < ROWS_PER_BLOCK; ++r) {
        int n = rbase + r;
        unsigned long long p = bestpack[n];
        int idx = (int)(p & 0xFFFFFFFFull);
        float f = z[n * D + tx];
        float q = ET[idx * D + tx];
        out_q[n * D + tx] = q;
        float dd = q - f;
        part += dd * dd;
        atomicAdd(&esumT[idx * D + tx], f);
        if (tx == 0) {
            atomicAdd(&counts[idx], 1.0f);
            out_ind[n] = (float)idx;
        }
    }
#pragma unroll
    for (int off = 32; off; off >>= 1) part += __shfl_down(part, off);
    __shared__ float wsum[4];
    if ((tx & 63) == 0) wsum[tx >> 6] = part;
    __syncthreads();
    if (tx == 0) {
        float t = wsum[0] + wsum[1] + wsum[2] + wsum[3];
        atomicAdd(out_diff, t * (0.25f / 8388608.0f));
    }
}

// ---------- cluster_size_new + total n ----------
__global__ __launch_bounds__(1024)
void csn_sum(const float* __restrict__ cs_in, const float* __restrict__ counts,
             float* __restrict__ csn, float* __restrict__ nsum) {
    const float decay = 0.99f;
    const float omd = 0.01f;
    int tx = threadIdx.x;
    float p = 0.f;
    for (int k = tx; k < K; k += 1024) {
        float v = decay * cs_in[k] + omd * counts[k];
        csn[k] = v;
        p += v;
    }
#pragma unroll
    for (int off = 32; off; off >>= 1) p += __shfl_down(p, off);
    __shared__ float red[16];
    if ((tx & 63) == 0) red[tx >> 6] = p;
    __syncthreads();
    if (tx == 0) {
        float t = 0.f;
        for (int i = 0; i < 16; ++i) t += red[i];
        nsum[0] = t;
    }
}

// ---------- embed_new = (decay*eavg + (1-decay)*esum) / cs ----------
__global__ __launch_bounds__(256)
void finalize(const float* __restrict__ eavg, const float* __restrict__ esumT,
              const float* __restrict__ csn, const float* __restrict__ nsum,
              float* __restrict__ out_enew) {
    const float decay = 0.99f;
    const float omd = 0.01f;
    const float keps = (float)(8192 * 1e-5);
    int idx = blockIdx.x * 256 + threadIdx.x;  // d*K + k
    float nv = nsum[0];
    int k = idx & (K - 1);
    int d = idx >> 13;
    float avg_new = decay * eavg[idx] + omd * esumT[k * D + d];
    float cs = (csn[k] + 1e-5f) / (nv + keps) * nv;
    out_enew[idx] = avg_new / cs;
}

extern "C" void kernel_launch(void* const* d_in, const int* in_sizes, int n_in,
                              void* d_out, int out_size, void* d_ws, size_t ws_size,
                              hipStream_t stream) {
    const float* z = (const float*)d_in[0];      // [32,32,32,256]
    const float* embed = (const float*)d_in[1];  // [256, 8192]
    const float* cs_in = (const float*)d_in[2];  // [8192]
    const float* eavg = (const float*)d_in[3];   // [256, 8192]

    float* out = (float*)d_out;
    float* out_q = out;                  // 8388608
    float* out_diff = out + 8388608;     // 1
    float* out_ind = out + 8388609;      // 32768
    float* out_enew = out + 8421377;     // 2097152

    char* ws = (char*)d_ws;
    unsigned long long* bestpack = (unsigned long long*)ws;      // 256 KB
    float* enorm = (float*)(ws + 262144);                        // 32 KB
    float* counts = (float*)(ws + 294912);                       // 32 KB
    float* csn = (float*)(ws + 327680);                          // 32 KB
    float* nsum = (float*)(ws + 360448);                         // pad
    float* esumT = (float*)(ws + 360704);                        // 8 MB [K,D]
    unsigned short* Fhi = (unsigned short*)(ws + 8749312);       // 16 MB
    unsigned short* Flo = (unsigned short*)(ws + 25526528);      // 16 MB
    unsigned short* EhiT = (unsigned short*)(ws + 42303744);     // 4 MB
    unsigned short* EloT = (unsigned short*)(ws + 46498048);     // 4 MB
    float* ET = (float*)(ws + 50692352);                         // 8 MB

    hipMemsetAsync(bestpack, 0xFF, NTOT * 8, stream);
    hipMemsetAsync(counts, 0, K * 4, stream);
    hipMemsetAsync(esumT, 0, K * D * 4, stream);
    hipMemsetAsync(out_diff, 0, 4, stream);

    conv_F<<<NTOT * D / 4 / 256, 256, 0, stream>>>(z, Fhi, Flo);
    conv_E<<<dim3(K / 64, D / 64), 256, 0, stream>>>(embed, EhiT, EloT, ET, enorm);
    enorm_kernel<<<K / 256, 256, 0, stream>>>(ET, enorm);
    mfma_dist_argmin<<<dim3(NTOT / BM, CSPLIT), 256, 0, stream>>>(Fhi, Flo, EhiT, EloT,
                                                                  enorm, bestpack);
    assign_apply<<<NTOT / ROWS_PER_BLOCK, 256, 0, stream>>>(z, ET, bestpack, out_q,
                                                            out_ind, out_diff, counts, esumT);
    csn_sum<<<1, 1024, 0, stream>>>(cs_in, counts, csn, nsum);
    finalize<<<(D * K) / 256, 256, 0, stream>>>(eavg, esumT, csn, nsum, out_enew);
}